// Round 7
// baseline (839.151 us; speedup 1.0000x reference)
//
#include <hip/hip_runtime.h>
#include <hip/hip_cooperative_groups.h>
#include <math.h>

namespace cg = cooperative_groups;

#define BB 8
#define NN 2048
#define FF 128
#define NP1 (NN + 1)
#define LALPHA 0.2f
#define CH 16
#define NCH (NN / CH)     // 128
#define NCP1 (NCH + 1)    // 129

#define NBLK 1024
#define NTHR 256

// ============================================================================
// Cooperative mega-kernel: 1024 blocks x 256 threads, 4 blocks/CU co-resident.
// P1 gemm -> P2 rank-sort(+exp) -> P3 chunk sums -> P4 chunk scan -> P5 emit.
// ============================================================================
__global__ __launch_bounds__(NTHR, 4)
void mega(const float* __restrict__ x, const float* __restrict__ W,
          const float* __restrict__ a,
          float* __restrict__ h, float* __restrict__ si, float* __restrict__ sj,
          float* __restrict__ keys, int* __restrict__ sidx,
          float* __restrict__ ew1, float* __restrict__ ew2,
          float* __restrict__ csum1, float* __restrict__ csum2,
          float* __restrict__ ssum1, float* __restrict__ ssum2,
          float* __restrict__ CS1, float* __restrict__ CP2,
          float* __restrict__ TS1, float* __restrict__ TP2,
          float* __restrict__ out)
{
    cg::grid_group grid = cg::this_grid();
    __shared__ float smem[8224];          // 32.9 KB; unioned across phases
    const int bid = blockIdx.x;
    const int t = threadIdx.x;

    //================ P1: h = x @ W^T, si = h.a1, sj = h.a2 ================
    // block = 16 rows; thread = 1 col x 8 rows; x via LDS broadcast, W via L2.
    {
        float* Xs = smem;                  // [16][132]
        float* sred = smem + 2112;         // [4 waves][8 rows][2]
        const int row0 = bid << 4;
        for (int kk = t; kk < 16 * FF; kk += NTHR) {
            int r = kk >> 7, f = kk & 127;
            Xs[r * 132 + f] = x[(size_t)row0 * FF + kk];
        }
        __syncthreads();
        const int o = t & 127;
        const int rg = t >> 7;             // rows rg*8 .. rg*8+7
        const float* Wrow = W + (size_t)o * FF;
        float acc[8];
#pragma unroll
        for (int r = 0; r < 8; ++r) acc[r] = 0.f;
#pragma unroll 2
        for (int f0 = 0; f0 < FF; f0 += 4) {
            float4 wv = *(const float4*)&Wrow[f0];
#pragma unroll
            for (int r = 0; r < 8; ++r) {
                float4 xv = *(const float4*)&Xs[(rg * 8 + r) * 132 + f0];
                acc[r] += xv.x * wv.x + xv.y * wv.y + xv.z * wv.z + xv.w * wv.w;
            }
        }
#pragma unroll
        for (int r = 0; r < 8; ++r)
            h[(size_t)(row0 + rg * 8 + r) * FF + o] = acc[r];

        const float a1o = a[o], a2o = a[FF + o];
        const int lane = t & 63, wid = t >> 6;
#pragma unroll
        for (int r = 0; r < 8; ++r) {
            float s1 = acc[r] * a1o;
            float s2 = acc[r] * a2o;
#pragma unroll
            for (int off = 32; off >= 1; off >>= 1) {
                s1 += __shfl_down(s1, off, 64);
                s2 += __shfl_down(s2, off, 64);
            }
            if (lane == 0) {
                sred[(wid * 8 + r) * 2]     = s1;
                sred[(wid * 8 + r) * 2 + 1] = s2;
            }
        }
        __syncthreads();
        if (t < 32) {
            int rl = t & 15, sel = t >> 4;          // row-local, 0=si 1=sj
            int rg2 = rl >> 3, r = rl & 7;
            float v = sred[((2 * rg2) * 8 + r) * 2 + sel]
                    + sred[((2 * rg2 + 1) * 8 + r) * 2 + sel];
            if (sel == 0) si[row0 + rl] = v; else sj[row0 + rl] = v;
        }
    }
    __threadfence();
    grid.sync();

    //================ P2: rank-sort sj per batch (+ exp weights) ================
    // block = (batch, 16-element segment); element ranked by 16 thread-slices.
    {
        float* lk = smem;                  // 2048
        const int b = bid >> 7, seg = bid & 127;
        for (int j = t; j < NN; j += NTHR) lk[j] = sj[b * NN + j];
        __syncthreads();
        const int el = t >> 4, slice = t & 15;
        const int e = (seg << 4) + el;
        const float ki = lk[e];
        const float4* lk4 = (const float4*)lk;
        int r = 0;
#pragma unroll 8
        for (int it = 0; it < 32; ++it) {
            int q = slice + (it << 4);
            float4 v = lk4[q];
            int j = q << 2;
            r += (v.x < ki || (v.x == ki && (j + 0) < e));
            r += (v.y < ki || (v.y == ki && (j + 1) < e));
            r += (v.z < ki || (v.z == ki && (j + 2) < e));
            r += (v.w < ki || (v.w == ki && (j + 3) < e));
        }
        r += __shfl_down(r, 8, 16);
        r += __shfl_down(r, 4, 16);
        r += __shfl_down(r, 2, 16);
        r += __shfl_down(r, 1, 16);
        if (slice == 0) {
            keys[b * NN + r] = ki;
            sidx[b * NN + r] = e;
            ew1[b * NN + r] = expf(ki);
            ew2[b * NN + r] = expf(LALPHA * ki);
        }
    }
    __threadfence();
    grid.sync();

    //================ P3: per-chunk weighted sums ================
    // block = (b, c); halves split the 16 gathers; LDS-combine.
    {
        const int b = bid >> 7, c = bid & 127;
        const int m0 = c << 4;
        float* lw1 = smem;                 // 16
        float* lw2 = smem + 16;            // 16
        int*   li  = (int*)(smem + 32);    // 16
        float* pa1 = smem + 64;            // [2][128]
        float* pa2 = smem + 320;           // [2][128]
        if (t < CH) {
            lw1[t] = ew1[b * NN + m0 + t];
            lw2[t] = ew2[b * NN + m0 + t];
            li[t]  = sidx[b * NN + m0 + t];
        }
        __syncthreads();
        const int o = t & 127, ht = t >> 7;
        float a1 = 0.f, a2 = 0.f;
#pragma unroll
        for (int m = ht * 8; m < ht * 8 + 8; ++m) {
            float hv = h[(size_t)(b * NN + li[m]) * FF + o];
            a1 += lw1[m] * hv;
            a2 += lw2[m] * hv;
        }
        pa1[ht * 128 + o] = a1;
        pa2[ht * 128 + o] = a2;
        __syncthreads();
        if (ht == 0) {
            csum1[(size_t)bid * FF + o] = pa1[o] + pa1[128 + o];
            csum2[(size_t)bid * FF + o] = pa2[o] + pa2[128 + o];
            if (o == 0) {
                float s1 = 0.f, s2 = 0.f;
#pragma unroll
                for (int m = 0; m < CH; ++m) { s1 += lw1[m]; s2 += lw2[m]; }
                ssum1[bid] = s1; ssum2[bid] = s2;
            }
        }
    }
    __threadfence();
    grid.sync();

    //================ P4: chunk-granular scanned sums ================
    // block = (b, c): ht0 -> CS1 (suffix over csum1), ht1 -> CP2 (prefix csum2).
    {
        const int b = bid >> 7, c = bid & 127;
        const int o = t & 127, ht = t >> 7;
        if (ht == 0) {
            float a1 = 0.f;
#pragma unroll 4
            for (int c2 = c; c2 < NCH; ++c2)
                a1 += csum1[(size_t)(b * NCH + c2) * FF + o];
            CS1[(size_t)(b * NCP1 + c) * FF + o] = a1;
            if (c == NCH - 1) CS1[(size_t)(b * NCP1 + NCH) * FF + o] = 0.f;
            if (o == 0) {
                float s = 0.f;
#pragma unroll 4
                for (int c2 = c; c2 < NCH; ++c2) s += ssum1[b * NCH + c2];
                TS1[b * NCP1 + c] = s;
                if (c == NCH - 1) TS1[b * NCP1 + NCH] = 0.f;
            }
        } else {
            float a2 = 0.f;
#pragma unroll 4
            for (int c2 = 0; c2 < c; ++c2)
                a2 += csum2[(size_t)(b * NCH + c2) * FF + o];
            CP2[(size_t)(b * NCP1 + c) * FF + o] = a2;
            if (c == NCH - 1)
                CP2[(size_t)(b * NCP1 + NCH) * FF + o] =
                    a2 + csum2[(size_t)(b * NCH + NCH - 1) * FF + o];
            if (o == 0) {
                float s = 0.f;
#pragma unroll 4
                for (int c2 = 0; c2 < c; ++c2) s += ssum2[b * NCH + c2];
                TP2[b * NCP1 + c] = s;
                if (c == NCH - 1) TP2[b * NCP1 + NCH] = s + ssum2[b * NCH + NCH - 1];
            }
        }
    }
    __threadfence();
    grid.sync();

    //================ P5: outputs ================
    // block = 16 rows; keys/weights/idx staged in LDS; 16 parallel searches;
    // per row: chunk bases from L2 + <=16 in-chunk h gathers.
    {
        const int b = bid >> 7, i0 = (bid & 127) << 4;
        float* lk  = smem;                 // 2048
        float* le1 = smem + 2048;          // 2048
        float* le2 = smem + 4096;          // 2048
        int*   li  = (int*)(smem + 6144);  // 2048
        int*   lp  = (int*)(smem + 8192);  // 16
        float* lsi = smem + 8208;          // 16
        for (int j = t; j < NN; j += NTHR) {
            lk[j]  = keys[b * NN + j];
            le1[j] = ew1[b * NN + j];
            le2[j] = ew2[b * NN + j];
            li[j]  = sidx[b * NN + j];
        }
        if (t < 16) lsi[t] = si[b * NN + i0 + t];
        __syncthreads();
        if (t < 16) {
            const float thr = -lsi[t];
            int lo = 0, hi = NN;
            while (lo < hi) {             // first m with key[m] >= -si
                int mid = (lo + hi) >> 1;
                if (lk[mid] < thr) lo = mid + 1; else hi = mid;
            }
            lp[t] = lo;
        }
        __syncthreads();
        const int o = t & 127, rh = t >> 7;
#pragma unroll
        for (int sub = 0; sub < 8; ++sub) {
            const int il = (sub << 1) + rh;
            const int p = lp[il];
            int c = p >> 4; if (c > NCH - 1) c = NCH - 1;
            const int rel = p - (c << 4);  // 0..16
            const int mb = c << 4;
            float acc1 = 0.f, acc2 = 0.f, sc1 = 0.f, sc2 = 0.f;
#pragma unroll
            for (int m = 0; m < CH; ++m) { // rel uniform per half-block
                float hv = h[(size_t)(b * NN + li[mb + m]) * FF + o];
                float w1 = le1[mb + m], w2 = le2[mb + m];
                if (m >= rel) { acc1 += w1 * hv; sc1 += w1; }
                else          { acc2 += w2 * hv; sc2 += w2; }
            }
            const float siv = lsi[il];
            const float e1 = expf(siv), e2 = expf(LALPHA * siv);
            const float S1v = CS1[(size_t)(b * NCP1 + c + 1) * FF + o] + acc1;
            const float P2v = CP2[(size_t)(b * NCP1 + c) * FF + o] + acc2;
            const float den = e1 * (TS1[b * NCP1 + c + 1] + sc1)
                            + e2 * (TP2[b * NCP1 + c] + sc2);
            out[(size_t)(b * NN + i0 + il) * FF + o] = (e1 * S1v + e2 * P2v) / den;
        }
    }
}

// ============================================================================
// Fallback pipeline (R6, proven 69.7 us) — used only if cooperative launch
// is rejected (e.g. by graph capture).
// ============================================================================
#define K1R 64
__global__ __launch_bounds__(256, 1)
void k1_h(const float* __restrict__ x, const float* __restrict__ W,
          const float* __restrict__ a, float* __restrict__ h,
          float* __restrict__ si, float* __restrict__ sj)
{
    __shared__ float Wt[FF * 132];
    __shared__ float Xt[FF * 68];
    const int t = threadIdx.x;
    const int row0 = blockIdx.x * K1R;

    for (int kk = t; kk < FF * FF; kk += 256) {
        int o = kk >> 7, f = kk & (FF - 1);
        Wt[f * 132 + o] = W[kk];
    }
    for (int kk = t; kk < K1R * FF; kk += 256) {
        int r = kk >> 7, f = kk & (FF - 1);
        Xt[f * 68 + r] = x[(row0 + r) * FF + f];
    }
    __syncthreads();

    const int tx = t & 15, ty = t >> 4;
    const int oq = tx << 3;
    const int rq = ty << 2;
    float acc[4][8];
#pragma unroll
    for (int r = 0; r < 4; ++r)
#pragma unroll
        for (int c = 0; c < 8; ++c) acc[r][c] = 0.f;

#pragma unroll 4
    for (int f = 0; f < FF; ++f) {
        float4 xv = *(const float4*)&Xt[f * 68 + rq];
        float4 w0 = *(const float4*)&Wt[f * 132 + oq];
        float4 w1 = *(const float4*)&Wt[f * 132 + oq + 4];
        const float xr[4] = {xv.x, xv.y, xv.z, xv.w};
        const float wc[8] = {w0.x, w0.y, w0.z, w0.w, w1.x, w1.y, w1.z, w1.w};
#pragma unroll
        for (int r = 0; r < 4; ++r)
#pragma unroll
            for (int c = 0; c < 8; ++c)
                acc[r][c] += xr[r] * wc[c];
    }
#pragma unroll
    for (int r = 0; r < 4; ++r) {
        float* hp = &h[(size_t)(row0 + rq + r) * FF + oq];
        *(float4*)hp       = make_float4(acc[r][0], acc[r][1], acc[r][2], acc[r][3]);
        *(float4*)(hp + 4) = make_float4(acc[r][4], acc[r][5], acc[r][6], acc[r][7]);
    }
    const float4 a10 = *(const float4*)&a[oq];
    const float4 a11 = *(const float4*)&a[oq + 4];
    const float4 a20 = *(const float4*)&a[FF + oq];
    const float4 a21 = *(const float4*)&a[FF + oq + 4];
    const float a1v[8] = {a10.x, a10.y, a10.z, a10.w, a11.x, a11.y, a11.z, a11.w};
    const float a2v[8] = {a20.x, a20.y, a20.z, a20.w, a21.x, a21.y, a21.z, a21.w};
#pragma unroll
    for (int r = 0; r < 4; ++r) {
        float s1 = 0.f, s2 = 0.f;
#pragma unroll
        for (int c = 0; c < 8; ++c) { s1 += acc[r][c] * a1v[c]; s2 += acc[r][c] * a2v[c]; }
#pragma unroll
        for (int off = 8; off >= 1; off >>= 1) {
            s1 += __shfl_down(s1, off, 16);
            s2 += __shfl_down(s2, off, 16);
        }
        if (tx == 0) { si[row0 + rq + r] = s1; sj[row0 + rq + r] = s2; }
    }
}

__global__ __launch_bounds__(1024)
void k2_rank(const float* __restrict__ sj, float* __restrict__ keys, int* __restrict__ sidx)
{
    __shared__ float lk[NN];
    const int b = blockIdx.x >> 4;
    const int s = blockIdx.x & 15;
    const int t = threadIdx.x;
    for (int j = t; j < NN; j += 1024) lk[j] = sj[b * NN + j];
    __syncthreads();
    const int e = s * 128 + (t >> 3);
    const int slice = t & 7;
    const float ki = lk[e];
    const float4* lk4 = (const float4*)lk;
    int r = 0;
#pragma unroll 8
    for (int it = 0; it < 64; ++it) {
        int q = slice + (it << 3);
        float4 v = lk4[q];
        int j = q << 2;
        r += (v.x < ki || (v.x == ki && (j + 0) < e));
        r += (v.y < ki || (v.y == ki && (j + 1) < e));
        r += (v.z < ki || (v.z == ki && (j + 2) < e));
        r += (v.w < ki || (v.w == ki && (j + 3) < e));
    }
    r += __shfl_down(r, 4, 8);
    r += __shfl_down(r, 2, 8);
    r += __shfl_down(r, 1, 8);
    if (slice == 0) { keys[b * NN + r] = ki; sidx[b * NN + r] = e; }
}

__global__ __launch_bounds__(128)
void k3a_csum(const float* __restrict__ h, const float* __restrict__ keys,
              const int* __restrict__ sidx,
              float* __restrict__ csum1, float* __restrict__ csum2,
              float* __restrict__ ssum1, float* __restrict__ ssum2)
{
    const int bid = blockIdx.x;
    const int b = bid >> 7, c = bid & (NCH - 1);
    const int o = threadIdx.x;
    const int m0 = c * CH;
    __shared__ float lw1[CH], lw2[CH];
    __shared__ int li[CH];
    if (o < CH) {
        float kv = keys[b * NN + m0 + o];
        lw1[o] = expf(kv);
        lw2[o] = expf(LALPHA * kv);
        li[o] = sidx[b * NN + m0 + o];
    }
    __syncthreads();
    float r[CH];
#pragma unroll
    for (int m = 0; m < CH; ++m)
        r[m] = h[(size_t)(b * NN + li[m]) * FF + o];
    float a1 = 0.f, a2 = 0.f, s1 = 0.f, s2 = 0.f;
#pragma unroll
    for (int m = 0; m < CH; ++m) {
        float w1 = lw1[m], w2 = lw2[m];
        a1 += w1 * r[m]; a2 += w2 * r[m];
        s1 += w1;        s2 += w2;
    }
    csum1[(size_t)bid * FF + o] = a1;
    csum2[(size_t)bid * FF + o] = a2;
    if (o == 0) { ssum1[bid] = s1; ssum2[bid] = s2; }
}

__global__ __launch_bounds__(128)
void k3sp_fill(const float* __restrict__ h, const float* __restrict__ keys,
               const int* __restrict__ sidx,
               const float* __restrict__ csum1, const float* __restrict__ csum2,
               const float* __restrict__ ssum1, const float* __restrict__ ssum2,
               float* __restrict__ S1, float* __restrict__ P2,
               float* __restrict__ T1, float* __restrict__ T2)
{
    const int bid = blockIdx.x;
    const int b = bid >> 7, c = bid & (NCH - 1);
    const int o = threadIdx.x;
    const int m0 = c * CH;
    __shared__ float lw1[CH], lw2[CH];
    __shared__ int li[CH];
    if (o < CH) {
        float kv = keys[b * NN + m0 + o];
        lw1[o] = expf(kv);
        lw2[o] = expf(LALPHA * kv);
        li[o] = sidx[b * NN + m0 + o];
    }
    __syncthreads();
    float r[CH];
#pragma unroll
    for (int m = 0; m < CH; ++m)
        r[m] = h[(size_t)(b * NN + li[m]) * FF + o];
    float bS1 = 0.f, tS1 = 0.f;
#pragma unroll 4
    for (int c2 = c + 1; c2 < NCH; ++c2) {
        bS1 += csum1[(size_t)(b * NCH + c2) * FF + o];
        tS1 += ssum1[b * NCH + c2];
    }
    float bP2 = 0.f, tP2 = 0.f;
#pragma unroll 4
    for (int c2 = 0; c2 < c; ++c2) {
        bP2 += csum2[(size_t)(b * NCH + c2) * FF + o];
        tP2 += ssum2[b * NCH + c2];
    }
    float acc = bS1, sacc = tS1;
#pragma unroll
    for (int m = CH - 1; m >= 0; --m) {
        acc += lw1[m] * r[m]; sacc += lw1[m];
        S1[(size_t)(b * NP1 + m0 + m) * FF + o] = acc;
        if (o == 0) T1[b * NP1 + m0 + m] = sacc;
    }
    float acc2 = bP2, sacc2 = tP2;
#pragma unroll
    for (int m = 0; m < CH; ++m) {
        P2[(size_t)(b * NP1 + m0 + m) * FF + o] = acc2;
        if (o == 0) T2[b * NP1 + m0 + m] = sacc2;
        acc2 += lw2[m] * r[m]; sacc2 += lw2[m];
    }
    if (c == NCH - 1) {
        S1[(size_t)(b * NP1 + NN) * FF + o] = 0.f;
        P2[(size_t)(b * NP1 + NN) * FF + o] = acc2;
        if (o == 0) { T1[b * NP1 + NN] = 0.f; T2[b * NP1 + NN] = sacc2; }
    }
}

__global__ __launch_bounds__(128)
void k4_out(const float* __restrict__ si, const float* __restrict__ keys,
            const float* __restrict__ S1, const float* __restrict__ P2,
            const float* __restrict__ T1, const float* __restrict__ T2,
            float* __restrict__ out)
{
    const int bi = blockIdx.x;
    const int b = bi >> 11, i = bi & (NN - 1);
    const int o = threadIdx.x;
    const float siv = si[b * NN + i];
    const float thr = -siv;
    const float* kb = keys + b * NN;
    int lo = 0, hi = NN;
    while (lo < hi) {
        int mid = (lo + hi) >> 1;
        if (kb[mid] < thr) lo = mid + 1; else hi = mid;
    }
    const int p = lo;
    const float e1 = expf(siv), e2 = expf(LALPHA * siv);
    const float num = e1 * S1[(size_t)(b * NP1 + p) * FF + o]
                    + e2 * P2[(size_t)(b * NP1 + p) * FF + o];
    const float den = e1 * T1[b * NP1 + p] + e2 * T2[b * NP1 + p];
    out[(size_t)(b * NN + i) * FF + o] = num / den;
}

extern "C" void kernel_launch(void* const* d_in, const int* in_sizes, int n_in,
                              void* d_out, int out_size, void* d_ws, size_t ws_size,
                              hipStream_t stream)
{
    const float* x = (const float*)d_in[0];
    const float* W = (const float*)d_in[1];
    const float* a = (const float*)d_in[2];
    float* out = (float*)d_out;

    float* ws = (float*)d_ws;
    float* h     = ws;                           // B*N*F
    float* si    = h + BB * NN * FF;             // B*N
    float* sj    = si + BB * NN;                 // B*N
    float* keys  = sj + BB * NN;                 // B*N
    int*   sidx  = (int*)(keys + BB * NN);       // B*N
    float* ew1   = (float*)(sidx + BB * NN);     // B*N
    float* ew2   = ew1 + BB * NN;                // B*N
    float* csum1 = ew2 + BB * NN;                // B*NCH*F
    float* csum2 = csum1 + BB * NCH * FF;        // B*NCH*F
    float* ssum1 = csum2 + BB * NCH * FF;        // B*NCH
    float* ssum2 = ssum1 + BB * NCH;             // B*NCH
    float* CS1   = ssum2 + BB * NCH;             // B*NCP1*F
    float* CP2   = CS1 + BB * NCP1 * FF;         // B*NCP1*F
    float* TS1   = CP2 + BB * NCP1 * FF;         // B*NCP1
    float* TP2   = TS1 + BB * NCP1;              // B*NCP1
    // fallback-only arrays
    float* S1f   = TP2 + BB * NCP1;              // B*NP1*F
    float* P2f   = S1f + BB * NP1 * FF;          // B*NP1*F
    float* T1f   = P2f + BB * NP1 * FF;          // B*NP1
    float* T2f   = T1f + BB * NP1;               // B*NP1

    void* args[] = {
        (void*)&x, (void*)&W, (void*)&a,
        (void*)&h, (void*)&si, (void*)&sj,
        (void*)&keys, (void*)&sidx,
        (void*)&ew1, (void*)&ew2,
        (void*)&csum1, (void*)&csum2,
        (void*)&ssum1, (void*)&ssum2,
        (void*)&CS1, (void*)&CP2,
        (void*)&TS1, (void*)&TP2,
        (void*)&out
    };
    hipError_t err = hipLaunchCooperativeKernel((void*)mega, dim3(NBLK), dim3(NTHR),
                                                args, 0, stream);
    if (err != hipSuccess) {
        (void)hipGetLastError();   // clear error state; use proven 5-kernel path
        hipLaunchKernelGGL(k1_h, dim3(BB * NN / K1R), dim3(256), 0, stream, x, W, a, h, si, sj);
        hipLaunchKernelGGL(k2_rank, dim3(BB * 16), dim3(1024), 0, stream, sj, keys, sidx);
        hipLaunchKernelGGL(k3a_csum, dim3(BB * NCH), dim3(128), 0, stream, h, keys, sidx, csum1, csum2, ssum1, ssum2);
        hipLaunchKernelGGL(k3sp_fill, dim3(BB * NCH), dim3(128), 0, stream, h, keys, sidx, csum1, csum2, ssum1, ssum2, S1f, P2f, T1f, T2f);
        hipLaunchKernelGGL(k4_out, dim3(BB * NN), dim3(128), 0, stream, si, keys, S1f, P2f, T1f, T2f, out);
    }
}

// Round 8
// 74.293 us; speedup vs baseline: 11.2951x; 11.2951x over previous
//
#include <hip/hip_runtime.h>
#include <math.h>

#define BB 8
#define NN 2048
#define FF 128
#define LALPHA 0.2f
#define CH 16
#define NCH (NN / CH)     // 128

// ---------------- K1: h = x @ W^T, si = h.a1, sj = h.a2 (+ zero cnt) ----------------
// 256 blocks (1/CU) x 256 threads; 64 rows x 128 cols; thread tile 4x8.
#define K1R 64
__global__ __launch_bounds__(256, 1)
void k1_h(const float* __restrict__ x, const float* __restrict__ W,
          const float* __restrict__ a, float* __restrict__ h,
          float* __restrict__ si, float* __restrict__ sj, int* __restrict__ cnt)
{
    __shared__ float Wt[FF * 132];
    __shared__ float Xt[FF * 68];
    const int t = threadIdx.x;
    const int row0 = blockIdx.x * K1R;

    if (blockIdx.x == 0)
        for (int kk = t; kk < BB * NCH; kk += 256) cnt[kk] = 0;

    for (int kk = t; kk < FF * FF; kk += 256) {
        int o = kk >> 7, f = kk & (FF - 1);
        Wt[f * 132 + o] = W[kk];
    }
    for (int kk = t; kk < K1R * FF; kk += 256) {
        int r = kk >> 7, f = kk & (FF - 1);
        Xt[f * 68 + r] = x[(row0 + r) * FF + f];
    }
    __syncthreads();

    const int tx = t & 15, ty = t >> 4;
    const int oq = tx << 3;
    const int rq = ty << 2;
    float acc[4][8];
#pragma unroll
    for (int r = 0; r < 4; ++r)
#pragma unroll
        for (int c = 0; c < 8; ++c) acc[r][c] = 0.f;

#pragma unroll 4
    for (int f = 0; f < FF; ++f) {
        float4 xv = *(const float4*)&Xt[f * 68 + rq];
        float4 w0 = *(const float4*)&Wt[f * 132 + oq];
        float4 w1 = *(const float4*)&Wt[f * 132 + oq + 4];
        const float xr[4] = {xv.x, xv.y, xv.z, xv.w};
        const float wc[8] = {w0.x, w0.y, w0.z, w0.w, w1.x, w1.y, w1.z, w1.w};
#pragma unroll
        for (int r = 0; r < 4; ++r)
#pragma unroll
            for (int c = 0; c < 8; ++c)
                acc[r][c] += xr[r] * wc[c];
    }
#pragma unroll
    for (int r = 0; r < 4; ++r) {
        float* hp = &h[(size_t)(row0 + rq + r) * FF + oq];
        *(float4*)hp       = make_float4(acc[r][0], acc[r][1], acc[r][2], acc[r][3]);
        *(float4*)(hp + 4) = make_float4(acc[r][4], acc[r][5], acc[r][6], acc[r][7]);
    }
    const float4 a10 = *(const float4*)&a[oq];
    const float4 a11 = *(const float4*)&a[oq + 4];
    const float4 a20 = *(const float4*)&a[FF + oq];
    const float4 a21 = *(const float4*)&a[FF + oq + 4];
    const float a1v[8] = {a10.x, a10.y, a10.z, a10.w, a11.x, a11.y, a11.z, a11.w};
    const float a2v[8] = {a20.x, a20.y, a20.z, a20.w, a21.x, a21.y, a21.z, a21.w};
#pragma unroll
    for (int r = 0; r < 4; ++r) {
        float s1 = 0.f, s2 = 0.f;
#pragma unroll
        for (int c = 0; c < 8; ++c) { s1 += acc[r][c] * a1v[c]; s2 += acc[r][c] * a2v[c]; }
#pragma unroll
        for (int off = 8; off >= 1; off >>= 1) {
            s1 += __shfl_down(s1, off, 16);
            s2 += __shfl_down(s2, off, 16);
        }
        if (tx == 0) { si[row0 + rq + r] = s1; sj[row0 + rq + r] = s2; }
    }
}

// ---------------- K2: rank-sort sj per batch (+ exp weights) ----------------
// grid = B*16 blocks, 1024 threads; element ranked by 8 bank-interleaved slices.
__global__ __launch_bounds__(1024)
void k2_rank(const float* __restrict__ sj, float* __restrict__ keys, int* __restrict__ sidx,
             float* __restrict__ ew1, float* __restrict__ ew2)
{
    __shared__ float lk[NN];
    const int b = blockIdx.x >> 4;
    const int s = blockIdx.x & 15;
    const int t = threadIdx.x;
    for (int j = t; j < NN; j += 1024) lk[j] = sj[b * NN + j];
    __syncthreads();
    const int e = s * 128 + (t >> 3);
    const int slice = t & 7;
    const float ki = lk[e];
    const float4* lk4 = (const float4*)lk;
    int r = 0;
#pragma unroll 8
    for (int it = 0; it < 64; ++it) {
        int q = slice + (it << 3);
        float4 v = lk4[q];
        int j = q << 2;
        r += (v.x < ki || (v.x == ki && (j + 0) < e));
        r += (v.y < ki || (v.y == ki && (j + 1) < e));
        r += (v.z < ki || (v.z == ki && (j + 2) < e));
        r += (v.w < ki || (v.w == ki && (j + 3) < e));
    }
    r += __shfl_down(r, 4, 8);
    r += __shfl_down(r, 2, 8);
    r += __shfl_down(r, 1, 8);
    if (slice == 0) {
        keys[b * NN + r] = ki;
        sidx[b * NN + r] = e;
        ew1[b * NN + r] = expf(ki);
        ew2[b * NN + r] = expf(LALPHA * ki);
    }
}

// ---------------- K3a: chunk sums + row bucketing ----------------
// grid = B*NCH = 1024 blocks, 128 threads.
__global__ __launch_bounds__(128)
void k3a_csum(const float* __restrict__ h, const float* __restrict__ keys,
              const int* __restrict__ sidx, const float* __restrict__ si,
              const float* __restrict__ ew1, const float* __restrict__ ew2,
              float* __restrict__ csum1, float* __restrict__ csum2,
              float* __restrict__ ssum1, float* __restrict__ ssum2,
              int* __restrict__ cnt, int* __restrict__ brows)
{
    const int bid = blockIdx.x;
    const int b = bid >> 7, c = bid & (NCH - 1);
    const int o = threadIdx.x;
    const int m0 = c * CH;

    __shared__ float lw1[CH], lw2[CH];
    __shared__ int li[CH];
    __shared__ float bkey[NCH];
    if (o < CH) {
        lw1[o] = ew1[b * NN + m0 + o];
        lw2[o] = ew2[b * NN + m0 + o];
        li[o]  = sidx[b * NN + m0 + o];
    }
    bkey[o] = keys[b * NN + (o << 4)];     // chunk boundary keys
    __syncthreads();

    float r[CH];
#pragma unroll
    for (int m = 0; m < CH; ++m)
        r[m] = h[(size_t)(b * NN + li[m]) * FF + o];

    float a1 = 0.f, a2 = 0.f, s1 = 0.f, s2 = 0.f;
#pragma unroll
    for (int m = 0; m < CH; ++m) {
        float w1 = lw1[m], w2 = lw2[m];
        a1 += w1 * r[m]; a2 += w2 * r[m];
        s1 += w1;        s2 += w2;
    }
    csum1[(size_t)bid * FF + o] = a1;
    csum2[(size_t)bid * FF + o] = a2;
    if (o == 0) { ssum1[bid] = s1; ssum2[bid] = s2; }

    // bucketing: 16 rows (this block's row-chunk) x 8 boundary slices
    const int rl = o >> 3, slice = o & 7;
    const int i = m0 + rl;
    const float thr = -si[b * NN + i];
    int cc = 0;
#pragma unroll
    for (int k = 0; k < 16; ++k) {
        int c2 = slice * 16 + k;
        cc += (c2 >= 1) && (bkey[c2] < thr);   // count boundaries strictly below thr
    }
    cc += __shfl_down(cc, 4, 8);
    cc += __shfl_down(cc, 2, 8);
    cc += __shfl_down(cc, 1, 8);
    if (slice == 0) {
        int pos = atomicAdd(&cnt[b * NCH + cc], 1);
        brows[(size_t)(b * NCH + cc) * NN + pos] = i;
    }
}

// ---------------- K4: emit — own bases + LDS-chunk corrections ----------------
// grid = B*NCH = 1024 blocks, 256 threads (2 half-blocks of 128).
__global__ __launch_bounds__(256)
void k4_emit(const float* __restrict__ h, const float* __restrict__ keys,
             const int* __restrict__ sidx, const float* __restrict__ si,
             const float* __restrict__ ew1, const float* __restrict__ ew2,
             const float* __restrict__ csum1, const float* __restrict__ csum2,
             const float* __restrict__ ssum1, const float* __restrict__ ssum2,
             const int* __restrict__ cnt, const int* __restrict__ brows,
             float* __restrict__ out)
{
    __shared__ float hs[CH][FF];      // 8 KB: the chunk's 16 h-rows
    __shared__ float lkey[CH], lw1[CH], lw2[CH];
    __shared__ float bS1[FF], bP2[FF];
    __shared__ float tS[2];

    const int bid = blockIdx.x;
    const int b = bid >> 7, c = bid & (NCH - 1);
    const int t = threadIdx.x;
    const int o = t & 127, ht = t >> 7;
    const int m0 = c * CH;

    if (t < CH) {
        lkey[t] = keys[b * NN + m0 + t];
        lw1[t]  = ew1[b * NN + m0 + t];
        lw2[t]  = ew2[b * NN + m0 + t];
    }
    // stage 16 h-rows (each 128-thread group loads one row; sidx broadcast-read)
    for (int kk = t; kk < CH * FF; kk += 256) {
        int m = kk >> 7, f = kk & 127;
        hs[m][f] = h[(size_t)(b * NN + sidx[b * NN + m0 + m]) * FF + f];
    }
    // own chunk-granular bases: ht0 -> suffix of csum1, ht1 -> prefix of csum2
    if (ht == 0) {
        float a1 = 0.f, s1 = 0.f;
#pragma unroll 4
        for (int c2 = c + 1; c2 < NCH; ++c2) {
            a1 += csum1[(size_t)(b * NCH + c2) * FF + o];
            s1 += ssum1[b * NCH + c2];
        }
        bS1[o] = a1;
        if (o == 0) tS[0] = s1;
    } else {
        float a2 = 0.f, s2 = 0.f;
#pragma unroll 4
        for (int c2 = 0; c2 < c; ++c2) {
            a2 += csum2[(size_t)(b * NCH + c2) * FF + o];
            s2 += ssum2[b * NCH + c2];
        }
        bP2[o] = a2;
        if (o == 0) tS[1] = s2;
    }
    __syncthreads();

    const int nrows = cnt[b * NCH + c];
    const int* br = brows + (size_t)(b * NCH + c) * NN;
    const float baseS1 = bS1[o], baseP2 = bP2[o];
    const float tS1 = tS[0], tP2 = tS[1];

    for (int r0 = 0; r0 < nrows; r0 += 2) {
        const int ri = r0 + ht;
        if (ri < nrows) {
            const int i = br[ri];
            const float siv = si[b * NN + i];
            const float thr = -siv;
            float acc1 = 0.f, acc2 = 0.f, sc1 = 0.f, sc2 = 0.f;
#pragma unroll
            for (int m = 0; m < CH; ++m) {
                float hv = hs[m][o];
                if (lkey[m] < thr) { acc2 += lw2[m] * hv; sc2 += lw2[m]; }  // prefix side
                else               { acc1 += lw1[m] * hv; sc1 += lw1[m]; }  // suffix side
            }
            const float e1 = expf(siv), e2 = expf(LALPHA * siv);
            const float num = e1 * (baseS1 + acc1) + e2 * (baseP2 + acc2);
            const float den = e1 * (tS1 + sc1) + e2 * (tP2 + sc2);
            out[(size_t)(b * NN + i) * FF + o] = num / den;
        }
    }
}

extern "C" void kernel_launch(void* const* d_in, const int* in_sizes, int n_in,
                              void* d_out, int out_size, void* d_ws, size_t ws_size,
                              hipStream_t stream)
{
    const float* x = (const float*)d_in[0];
    const float* W = (const float*)d_in[1];
    const float* a = (const float*)d_in[2];
    float* out = (float*)d_out;

    float* ws = (float*)d_ws;
    float* h     = ws;                           // B*N*F
    float* si    = h + BB * NN * FF;             // B*N
    float* sj    = si + BB * NN;                 // B*N
    float* keys  = sj + BB * NN;                 // B*N
    int*   sidx  = (int*)(keys + BB * NN);       // B*N
    float* ew1   = (float*)(sidx + BB * NN);     // B*N
    float* ew2   = ew1 + BB * NN;                // B*N
    float* csum1 = ew2 + BB * NN;                // B*NCH*F
    float* csum2 = csum1 + BB * NCH * FF;        // B*NCH*F
    float* ssum1 = csum2 + BB * NCH * FF;        // B*NCH
    float* ssum2 = ssum1 + BB * NCH;             // B*NCH
    int*   cnt   = (int*)(ssum2 + BB * NCH);     // B*NCH
    int*   brows = cnt + BB * NCH;               // B*NCH*N (8 MB)

    hipLaunchKernelGGL(k1_h, dim3(BB * NN / K1R), dim3(256), 0, stream, x, W, a, h, si, sj, cnt);
    hipLaunchKernelGGL(k2_rank, dim3(BB * 16), dim3(1024), 0, stream, sj, keys, sidx, ew1, ew2);
    hipLaunchKernelGGL(k3a_csum, dim3(BB * NCH), dim3(128), 0, stream,
                       h, keys, sidx, si, ew1, ew2, csum1, csum2, ssum1, ssum2, cnt, brows);
    hipLaunchKernelGGL(k4_emit, dim3(BB * NCH), dim3(256), 0, stream,
                       h, keys, sidx, si, ew1, ew2, csum1, csum2, ssum1, ssum2, cnt, brows, out);
}

// Round 9
// 67.678 us; speedup vs baseline: 12.3992x; 1.0977x over previous
//
#include <hip/hip_runtime.h>
#include <math.h>

#define BB 8
#define NN 2048
#define FF 128
#define LALPHA 0.2f
#define CH 16
#define NCH (NN / CH)     // 128

// ---------------- K1: h = x @ W^T, si = h.a1, sj = h.a2 (+ zero cnt) ----------------
// 256 blocks (1/CU) x 256 threads; 64 rows x 128 cols; thread tile 4x8.
#define K1R 64
__global__ __launch_bounds__(256, 1)
void k1_h(const float* __restrict__ x, const float* __restrict__ W,
          const float* __restrict__ a, float* __restrict__ h,
          float* __restrict__ si, float* __restrict__ sj, int* __restrict__ cnt)
{
    __shared__ float Wt[FF * 132];
    __shared__ float Xt[FF * 68];
    const int t = threadIdx.x;
    const int row0 = blockIdx.x * K1R;

    if (blockIdx.x == 0)
        for (int kk = t; kk < BB * NCH; kk += 256) cnt[kk] = 0;

    for (int kk = t; kk < FF * FF; kk += 256) {
        int o = kk >> 7, f = kk & (FF - 1);
        Wt[f * 132 + o] = W[kk];
    }
    for (int kk = t; kk < K1R * FF; kk += 256) {
        int r = kk >> 7, f = kk & (FF - 1);
        Xt[f * 68 + r] = x[(row0 + r) * FF + f];
    }
    __syncthreads();

    const int tx = t & 15, ty = t >> 4;
    const int oq = tx << 3;
    const int rq = ty << 2;
    float acc[4][8];
#pragma unroll
    for (int r = 0; r < 4; ++r)
#pragma unroll
        for (int c = 0; c < 8; ++c) acc[r][c] = 0.f;

#pragma unroll 4
    for (int f = 0; f < FF; ++f) {
        float4 xv = *(const float4*)&Xt[f * 68 + rq];
        float4 w0 = *(const float4*)&Wt[f * 132 + oq];
        float4 w1 = *(const float4*)&Wt[f * 132 + oq + 4];
        const float xr[4] = {xv.x, xv.y, xv.z, xv.w};
        const float wc[8] = {w0.x, w0.y, w0.z, w0.w, w1.x, w1.y, w1.z, w1.w};
#pragma unroll
        for (int r = 0; r < 4; ++r)
#pragma unroll
            for (int c = 0; c < 8; ++c)
                acc[r][c] += xr[r] * wc[c];
    }
#pragma unroll
    for (int r = 0; r < 4; ++r) {
        float* hp = &h[(size_t)(row0 + rq + r) * FF + oq];
        *(float4*)hp       = make_float4(acc[r][0], acc[r][1], acc[r][2], acc[r][3]);
        *(float4*)(hp + 4) = make_float4(acc[r][4], acc[r][5], acc[r][6], acc[r][7]);
    }
    const float4 a10 = *(const float4*)&a[oq];
    const float4 a11 = *(const float4*)&a[oq + 4];
    const float4 a20 = *(const float4*)&a[FF + oq];
    const float4 a21 = *(const float4*)&a[FF + oq + 4];
    const float a1v[8] = {a10.x, a10.y, a10.z, a10.w, a11.x, a11.y, a11.z, a11.w};
    const float a2v[8] = {a20.x, a20.y, a20.z, a20.w, a21.x, a21.y, a21.z, a21.w};
#pragma unroll
    for (int r = 0; r < 4; ++r) {
        float s1 = 0.f, s2 = 0.f;
#pragma unroll
        for (int c = 0; c < 8; ++c) { s1 += acc[r][c] * a1v[c]; s2 += acc[r][c] * a2v[c]; }
#pragma unroll
        for (int off = 8; off >= 1; off >>= 1) {
            s1 += __shfl_down(s1, off, 16);
            s2 += __shfl_down(s2, off, 16);
        }
        if (tx == 0) { si[row0 + rq + r] = s1; sj[row0 + rq + r] = s2; }
    }
}

// ---------------- K2: rank-sort sj per batch (+ exp weights) ----------------
__global__ __launch_bounds__(1024)
void k2_rank(const float* __restrict__ sj, float* __restrict__ keys, int* __restrict__ sidx,
             float* __restrict__ ew1, float* __restrict__ ew2)
{
    __shared__ float lk[NN];
    const int b = blockIdx.x >> 4;
    const int s = blockIdx.x & 15;
    const int t = threadIdx.x;
    for (int j = t; j < NN; j += 1024) lk[j] = sj[b * NN + j];
    __syncthreads();
    const int e = s * 128 + (t >> 3);
    const int slice = t & 7;
    const float ki = lk[e];
    const float4* lk4 = (const float4*)lk;
    int r = 0;
#pragma unroll 8
    for (int it = 0; it < 64; ++it) {
        int q = slice + (it << 3);
        float4 v = lk4[q];
        int j = q << 2;
        r += (v.x < ki || (v.x == ki && (j + 0) < e));
        r += (v.y < ki || (v.y == ki && (j + 1) < e));
        r += (v.z < ki || (v.z == ki && (j + 2) < e));
        r += (v.w < ki || (v.w == ki && (j + 3) < e));
    }
    r += __shfl_down(r, 4, 8);
    r += __shfl_down(r, 2, 8);
    r += __shfl_down(r, 1, 8);
    if (slice == 0) {
        keys[b * NN + r] = ki;
        sidx[b * NN + r] = e;
        ew1[b * NN + r] = expf(ki);
        ew2[b * NN + r] = expf(LALPHA * ki);
    }
}

// ---------------- K3a: chunk sums + row bucketing ----------------
__global__ __launch_bounds__(128)
void k3a_csum(const float* __restrict__ h, const float* __restrict__ keys,
              const int* __restrict__ sidx, const float* __restrict__ si,
              const float* __restrict__ ew1, const float* __restrict__ ew2,
              float* __restrict__ csum1, float* __restrict__ csum2,
              float* __restrict__ ssum1, float* __restrict__ ssum2,
              int* __restrict__ cnt, int* __restrict__ brows)
{
    const int bid = blockIdx.x;
    const int b = bid >> 7, c = bid & (NCH - 1);
    const int o = threadIdx.x;
    const int m0 = c * CH;

    __shared__ float lw1[CH], lw2[CH];
    __shared__ int li[CH];
    __shared__ float bkey[NCH];
    if (o < CH) {
        lw1[o] = ew1[b * NN + m0 + o];
        lw2[o] = ew2[b * NN + m0 + o];
        li[o]  = sidx[b * NN + m0 + o];
    }
    bkey[o] = keys[b * NN + (o << 4)];
    __syncthreads();

    float r[CH];
#pragma unroll
    for (int m = 0; m < CH; ++m)
        r[m] = h[(size_t)(b * NN + li[m]) * FF + o];

    float a1 = 0.f, a2 = 0.f, s1 = 0.f, s2 = 0.f;
#pragma unroll
    for (int m = 0; m < CH; ++m) {
        float w1 = lw1[m], w2 = lw2[m];
        a1 += w1 * r[m]; a2 += w2 * r[m];
        s1 += w1;        s2 += w2;
    }
    csum1[(size_t)bid * FF + o] = a1;
    csum2[(size_t)bid * FF + o] = a2;
    if (o == 0) { ssum1[bid] = s1; ssum2[bid] = s2; }

    // bucket rows m0..m0+15 (ORIGINAL indices) by chunk of their partition point
    const int rl = o >> 3, slice = o & 7;
    const int i = m0 + rl;
    const float thr = -si[b * NN + i];
    int cc = 0;
#pragma unroll
    for (int k = 0; k < 16; ++k) {
        int c2 = slice * 16 + k;
        cc += (c2 >= 1) && (bkey[c2] < thr);
    }
    cc += __shfl_down(cc, 4, 8);
    cc += __shfl_down(cc, 2, 8);
    cc += __shfl_down(cc, 1, 8);
    if (slice == 0) {
        int pos = atomicAdd(&cnt[b * NCH + cc], 1);
        brows[(size_t)(b * NCH + cc) * NN + pos] = i;
    }
}

// ---------------- K3se: bases + in-LDS per-position scan + direct emit ----------------
// grid = B*NCH = 1024 blocks, 256 threads (2 halves of 128).
__global__ __launch_bounds__(256)
void k3se_emit(const float* __restrict__ h, const float* __restrict__ keys,
               const int* __restrict__ sidx, const float* __restrict__ si,
               const float* __restrict__ ew1, const float* __restrict__ ew2,
               const float* __restrict__ csum1, const float* __restrict__ csum2,
               const float* __restrict__ ssum1, const float* __restrict__ ssum2,
               const int* __restrict__ cnt, const int* __restrict__ brows,
               float* __restrict__ out)
{
    __shared__ float hs[CH][FF];            // 8 KB
    __shared__ float S1pos[CH + 1][FF];     // 8.7 KB
    __shared__ float P2pos[CH + 1][FF];     // 8.7 KB
    __shared__ float lw1[CH], lw2[CH], lkey[CH];
    __shared__ float T1pos[CH + 1], T2pos[CH + 1];

    const int bid = blockIdx.x;
    const int b = bid >> 7, c = bid & (NCH - 1);
    const int t = threadIdx.x;
    const int o = t & 127, ht = t >> 7;
    const int m0 = c * CH;

    if (t < CH) {
        lkey[t] = keys[b * NN + m0 + t];
        lw1[t]  = ew1[b * NN + m0 + t];
        lw2[t]  = ew2[b * NN + m0 + t];
    }
    for (int kk = t; kk < CH * FF; kk += 256) {
        int m = kk >> 7, f = kk & 127;
        hs[m][f] = h[(size_t)(b * NN + sidx[b * NN + m0 + m]) * FF + f];
    }
    __syncthreads();

    if (ht == 0) {
        float a1 = 0.f;
#pragma unroll 4
        for (int c2 = c + 1; c2 < NCH; ++c2)
            a1 += csum1[(size_t)(b * NCH + c2) * FF + o];
        S1pos[CH][o] = a1;                 // suffix beyond this chunk
#pragma unroll
        for (int m = CH - 1; m >= 0; --m) {
            a1 += lw1[m] * hs[m][o];
            S1pos[m][o] = a1;              // inclusive suffix from m
        }
        if (o == 0) {
            float s = 0.f;
            for (int c2 = c + 1; c2 < NCH; ++c2) s += ssum1[b * NCH + c2];
            T1pos[CH] = s;
#pragma unroll
            for (int m = CH - 1; m >= 0; --m) { s += lw1[m]; T1pos[m] = s; }
        }
    } else {
        float a2 = 0.f;
#pragma unroll 4
        for (int c2 = 0; c2 < c; ++c2)
            a2 += csum2[(size_t)(b * NCH + c2) * FF + o];
        P2pos[0][o] = a2;                  // prefix of earlier chunks
#pragma unroll
        for (int m = 0; m < CH; ++m) {
            a2 += lw2[m] * hs[m][o];
            P2pos[m + 1][o] = a2;          // exclusive prefix at m+1
        }
        if (o == 0) {
            float s = 0.f;
            for (int c2 = 0; c2 < c; ++c2) s += ssum2[b * NCH + c2];
            T2pos[0] = s;
#pragma unroll
            for (int m = 0; m < CH; ++m) { s += lw2[m]; T2pos[m + 1] = s; }
        }
    }
    __syncthreads();

    const int nrows = cnt[b * NCH + c];
    const int* br = brows + (size_t)(b * NCH + c) * NN;

    for (int r0 = 0; r0 < nrows; r0 += 2) {
        const int ri = r0 + ht;
        if (ri < nrows) {
            const int i = br[ri];
            const float siv = si[b * NN + i];
            const float thr = -siv;
            int rel = 0;
#pragma unroll
            for (int m = 0; m < CH; ++m) rel += (lkey[m] < thr);
            const float e1 = expf(siv), e2 = expf(LALPHA * siv);
            const float num = e1 * S1pos[rel][o] + e2 * P2pos[rel][o];
            const float den = e1 * T1pos[rel] + e2 * T2pos[rel];
            out[(size_t)(b * NN + i) * FF + o] = num / den;
        }
    }
}

extern "C" void kernel_launch(void* const* d_in, const int* in_sizes, int n_in,
                              void* d_out, int out_size, void* d_ws, size_t ws_size,
                              hipStream_t stream)
{
    const float* x = (const float*)d_in[0];
    const float* W = (const float*)d_in[1];
    const float* a = (const float*)d_in[2];
    float* out = (float*)d_out;

    float* ws = (float*)d_ws;
    float* h     = ws;                           // B*N*F
    float* si    = h + BB * NN * FF;             // B*N
    float* sj    = si + BB * NN;                 // B*N
    float* keys  = sj + BB * NN;                 // B*N
    int*   sidx  = (int*)(keys + BB * NN);       // B*N
    float* ew1   = (float*)(sidx + BB * NN);     // B*N
    float* ew2   = ew1 + BB * NN;                // B*N
    float* csum1 = ew2 + BB * NN;                // B*NCH*F
    float* csum2 = csum1 + BB * NCH * FF;        // B*NCH*F
    float* ssum1 = csum2 + BB * NCH * FF;        // B*NCH
    float* ssum2 = ssum1 + BB * NCH;             // B*NCH
    int*   cnt   = (int*)(ssum2 + BB * NCH);     // B*NCH
    int*   brows = cnt + BB * NCH;               // B*NCH*N (8.4 MB)

    hipLaunchKernelGGL(k1_h, dim3(BB * NN / K1R), dim3(256), 0, stream, x, W, a, h, si, sj, cnt);
    hipLaunchKernelGGL(k2_rank, dim3(BB * 16), dim3(1024), 0, stream, sj, keys, sidx, ew1, ew2);
    hipLaunchKernelGGL(k3a_csum, dim3(BB * NCH), dim3(128), 0, stream,
                       h, keys, sidx, si, ew1, ew2, csum1, csum2, ssum1, ssum2, cnt, brows);
    hipLaunchKernelGGL(k3se_emit, dim3(BB * NCH), dim3(256), 0, stream,
                       h, keys, sidx, si, ew1, ew2, csum1, csum2, ssum1, ssum2, cnt, brows, out);
}

// Round 10
// 57.318 us; speedup vs baseline: 14.6403x; 1.1807x over previous
//
#include <hip/hip_runtime.h>
#include <math.h>

#define BB 8
#define NN 2048
#define FF 128
#define LALPHA 0.2f
#define CH 16
#define NCH (NN / CH)     // 128

// ---------------- K1: h = x @ W^T, si = h.a1, sj = h.a2 (+ zero cnt) ----------------
// 256 blocks (1/CU) x 256 threads; 64 rows x 128 cols; thread tile 4x8.
// W in LDS (67.6 KB); x read directly from global (L1-broadcast, ~8 MB total)
// -> 2 ds_read_b128 per f-iter instead of 3 (k1 is LDS-pipe-bound).
#define K1R 64
__global__ __launch_bounds__(256, 1)
void k1_h(const float* __restrict__ x, const float* __restrict__ W,
          const float* __restrict__ a, float* __restrict__ h,
          float* __restrict__ si, float* __restrict__ sj, int* __restrict__ cnt)
{
    __shared__ float Wt[FF * 132];
    const int t = threadIdx.x;
    const int row0 = blockIdx.x * K1R;

    if (blockIdx.x == 0)
        for (int kk = t; kk < BB * NCH; kk += 256) cnt[kk] = 0;

    for (int kk = t; kk < FF * FF; kk += 256) {
        int o = kk >> 7, f = kk & (FF - 1);
        Wt[f * 132 + o] = W[kk];
    }
    __syncthreads();

    const int tx = t & 15, ty = t >> 4;
    const int oq = tx << 3;
    const int rq = ty << 2;
    float acc[4][8];
#pragma unroll
    for (int r = 0; r < 4; ++r)
#pragma unroll
        for (int c = 0; c < 8; ++c) acc[r][c] = 0.f;

    for (int f0 = 0; f0 < FF; f0 += 4) {
        float4 xv[4];
#pragma unroll
        for (int r = 0; r < 4; ++r)
            xv[r] = *(const float4*)&x[(size_t)(row0 + rq + r) * FF + f0];
#pragma unroll
        for (int ff = 0; ff < 4; ++ff) {
            float4 w0 = *(const float4*)&Wt[(f0 + ff) * 132 + oq];
            float4 w1 = *(const float4*)&Wt[(f0 + ff) * 132 + oq + 4];
            const float wc[8] = {w0.x, w0.y, w0.z, w0.w, w1.x, w1.y, w1.z, w1.w};
#pragma unroll
            for (int r = 0; r < 4; ++r) {
                const float xr = (ff == 0) ? xv[r].x : (ff == 1) ? xv[r].y
                               : (ff == 2) ? xv[r].z : xv[r].w;
#pragma unroll
                for (int c = 0; c < 8; ++c)
                    acc[r][c] += xr * wc[c];
            }
        }
    }
#pragma unroll
    for (int r = 0; r < 4; ++r) {
        float* hp = &h[(size_t)(row0 + rq + r) * FF + oq];
        *(float4*)hp       = make_float4(acc[r][0], acc[r][1], acc[r][2], acc[r][3]);
        *(float4*)(hp + 4) = make_float4(acc[r][4], acc[r][5], acc[r][6], acc[r][7]);
    }
    const float4 a10 = *(const float4*)&a[oq];
    const float4 a11 = *(const float4*)&a[oq + 4];
    const float4 a20 = *(const float4*)&a[FF + oq];
    const float4 a21 = *(const float4*)&a[FF + oq + 4];
    const float a1v[8] = {a10.x, a10.y, a10.z, a10.w, a11.x, a11.y, a11.z, a11.w};
    const float a2v[8] = {a20.x, a20.y, a20.z, a20.w, a21.x, a21.y, a21.z, a21.w};
#pragma unroll
    for (int r = 0; r < 4; ++r) {
        float s1 = 0.f, s2 = 0.f;
#pragma unroll
        for (int c = 0; c < 8; ++c) { s1 += acc[r][c] * a1v[c]; s2 += acc[r][c] * a2v[c]; }
#pragma unroll
        for (int off = 8; off >= 1; off >>= 1) {
            s1 += __shfl_down(s1, off, 16);
            s2 += __shfl_down(s2, off, 16);
        }
        if (tx == 0) { si[row0 + rq + r] = s1; sj[row0 + rq + r] = s2; }
    }
}

// ---------------- K2: rank-sort sj per batch (+ exp weights) ----------------
// grid = B*32 = 256 blocks (full chip), 1024 threads; 16 slices per element.
__global__ __launch_bounds__(1024)
void k2_rank(const float* __restrict__ sj, float* __restrict__ keys, int* __restrict__ sidx,
             float* __restrict__ ew1, float* __restrict__ ew2)
{
    __shared__ float lk[NN];
    const int b = blockIdx.x >> 5;
    const int s = blockIdx.x & 31;
    const int t = threadIdx.x;
    for (int j = t; j < NN; j += 1024) lk[j] = sj[b * NN + j];
    __syncthreads();
    const int e = s * 64 + (t >> 4);
    const int slice = t & 15;
    const float ki = lk[e];
    const float4* lk4 = (const float4*)lk;
    int r = 0;
#pragma unroll 8
    for (int it = 0; it < 32; ++it) {
        int q = slice + (it << 4);
        float4 v = lk4[q];
        int j = q << 2;
        r += (v.x < ki || (v.x == ki && (j + 0) < e));
        r += (v.y < ki || (v.y == ki && (j + 1) < e));
        r += (v.z < ki || (v.z == ki && (j + 2) < e));
        r += (v.w < ki || (v.w == ki && (j + 3) < e));
    }
    r += __shfl_down(r, 8, 16);
    r += __shfl_down(r, 4, 16);
    r += __shfl_down(r, 2, 16);
    r += __shfl_down(r, 1, 16);
    if (slice == 0) {
        keys[b * NN + r] = ki;
        sidx[b * NN + r] = e;
        ew1[b * NN + r] = expf(ki);
        ew2[b * NN + r] = expf(LALPHA * ki);
    }
}

// ---------------- K3a: chunk sums + row bucketing ----------------
__global__ __launch_bounds__(128)
void k3a_csum(const float* __restrict__ h, const float* __restrict__ keys,
              const int* __restrict__ sidx, const float* __restrict__ si,
              const float* __restrict__ ew1, const float* __restrict__ ew2,
              float* __restrict__ csum1, float* __restrict__ csum2,
              float* __restrict__ ssum1, float* __restrict__ ssum2,
              int* __restrict__ cnt, int* __restrict__ brows)
{
    const int bid = blockIdx.x;
    const int b = bid >> 7, c = bid & (NCH - 1);
    const int o = threadIdx.x;
    const int m0 = c * CH;

    __shared__ float lw1[CH], lw2[CH];
    __shared__ int li[CH];
    __shared__ float bkey[NCH];
    if (o < CH) {
        lw1[o] = ew1[b * NN + m0 + o];
        lw2[o] = ew2[b * NN + m0 + o];
        li[o]  = sidx[b * NN + m0 + o];
    }
    bkey[o] = keys[b * NN + (o << 4)];
    __syncthreads();

    float r[CH];
#pragma unroll
    for (int m = 0; m < CH; ++m)
        r[m] = h[(size_t)(b * NN + li[m]) * FF + o];

    float a1 = 0.f, a2 = 0.f, s1 = 0.f, s2 = 0.f;
#pragma unroll
    for (int m = 0; m < CH; ++m) {
        float w1 = lw1[m], w2 = lw2[m];
        a1 += w1 * r[m]; a2 += w2 * r[m];
        s1 += w1;        s2 += w2;
    }
    csum1[(size_t)bid * FF + o] = a1;
    csum2[(size_t)bid * FF + o] = a2;
    if (o == 0) { ssum1[bid] = s1; ssum2[bid] = s2; }

    // bucket rows m0..m0+15 (ORIGINAL indices) by chunk of their partition point
    const int rl = o >> 3, slice = o & 7;
    const int i = m0 + rl;
    const float thr = -si[b * NN + i];
    int cc = 0;
#pragma unroll
    for (int k = 0; k < 16; ++k) {
        int c2 = slice * 16 + k;
        cc += (c2 >= 1) && (bkey[c2] < thr);
    }
    cc += __shfl_down(cc, 4, 8);
    cc += __shfl_down(cc, 2, 8);
    cc += __shfl_down(cc, 1, 8);
    if (slice == 0) {
        int pos = atomicAdd(&cnt[b * NCH + cc], 1);
        brows[(size_t)(b * NCH + cc) * NN + pos] = i;
    }
}

// ---------------- K3se: balanced bases + in-LDS scan + direct emit ----------------
// grid = B*NCH = 1024 blocks, 256 threads (2 halves of 128).
__global__ __launch_bounds__(256)
void k3se_emit(const float* __restrict__ h, const float* __restrict__ keys,
               const int* __restrict__ sidx, const float* __restrict__ si,
               const float* __restrict__ ew1, const float* __restrict__ ew2,
               const float* __restrict__ csum1, const float* __restrict__ csum2,
               const float* __restrict__ ssum1, const float* __restrict__ ssum2,
               const int* __restrict__ cnt, const int* __restrict__ brows,
               float* __restrict__ out)
{
    __shared__ float hs[CH][FF];            // 8 KB
    __shared__ float S1pos[CH + 1][FF];     // 8.7 KB
    __shared__ float P2pos[CH + 1][FF];     // 8.7 KB
    __shared__ float lw1[CH], lw2[CH], lkey[CH];
    __shared__ float T1pos[CH + 1], T2pos[CH + 1];
    __shared__ float ls1[NCH], ls2[NCH];    // staged scalar sums
    __shared__ float bp1[2][FF], bp2[2][FF];

    const int bid = blockIdx.x;
    const int b = bid >> 7, c = bid & (NCH - 1);
    const int t = threadIdx.x;
    const int o = t & 127, ht = t >> 7;
    const int m0 = c * CH;

    if (t < CH) {
        lkey[t] = keys[b * NN + m0 + t];
        lw1[t]  = ew1[b * NN + m0 + t];
        lw2[t]  = ew2[b * NN + m0 + t];
    }
    if (ht == 0) ls1[o] = ssum1[b * NCH + o];
    else         ls2[o] = ssum2[b * NCH + o];
    for (int kk = t; kk < CH * FF; kk += 256) {
        int m = kk >> 7, f = kk & 127;
        hs[m][f] = h[(size_t)(b * NN + sidx[b * NN + m0 + m]) * FF + f];
    }

    // balanced vector bases: thread (o, ht) covers c2 in [ht*64, ht*64+64)
    {
        const int c2lo = ht << 6, c2hi = c2lo + 64;
        float a1 = 0.f, a2 = 0.f;
        const int lo1 = (c + 1 > c2lo) ? c + 1 : c2lo;   // suffix side (csum1)
#pragma unroll 8
        for (int c2 = lo1; c2 < c2hi; ++c2)
            a1 += csum1[(size_t)(b * NCH + c2) * FF + o];
        const int hi2 = (c < c2hi) ? c : c2hi;           // prefix side (csum2)
#pragma unroll 8
        for (int c2 = c2lo; c2 < hi2; ++c2)
            a2 += csum2[(size_t)(b * NCH + c2) * FF + o];
        bp1[ht][o] = a1;
        bp2[ht][o] = a2;
    }
    __syncthreads();

    // vector scans (halves) + parallel scalar T (16 lanes each side)
    if (ht == 0) {
        float s = bp1[0][o] + bp1[1][o];
        S1pos[CH][o] = s;
#pragma unroll
        for (int m = CH - 1; m >= 0; --m) {
            s += lw1[m] * hs[m][o];
            S1pos[m][o] = s;
        }
        if (t < CH + 1) {
            float ts = 0.f;
#pragma unroll 8
            for (int c2 = c + 1; c2 < NCH; ++c2) ts += ls1[c2];
            for (int mm = CH - 1; mm >= t; --mm) ts += lw1[mm];
            T1pos[t] = ts;
        }
    } else {
        float s = bp2[0][o] + bp2[1][o];
        P2pos[0][o] = s;
#pragma unroll
        for (int m = 0; m < CH; ++m) {
            s += lw2[m] * hs[m][o];
            P2pos[m + 1][o] = s;
        }
        if (o < CH + 1) {
            float ts = 0.f;
#pragma unroll 8
            for (int c2 = 0; c2 < c; ++c2) ts += ls2[c2];
            for (int mm = 0; mm < o; ++mm) ts += lw2[mm];
            T2pos[o] = ts;
        }
    }
    __syncthreads();

    const int nrows = cnt[b * NCH + c];
    const int* br = brows + (size_t)(b * NCH + c) * NN;

    for (int r0 = 0; r0 < nrows; r0 += 2) {
        const int ri = r0 + ht;
        if (ri < nrows) {
            const int i = br[ri];
            const float siv = si[b * NN + i];
            const float thr = -siv;
            int rel = 0;
#pragma unroll
            for (int m = 0; m < CH; ++m) rel += (lkey[m] < thr);
            const float e1 = expf(siv), e2 = expf(LALPHA * siv);
            const float num = e1 * S1pos[rel][o] + e2 * P2pos[rel][o];
            const float den = e1 * T1pos[rel] + e2 * T2pos[rel];
            out[(size_t)(b * NN + i) * FF + o] = num / den;
        }
    }
}

extern "C" void kernel_launch(void* const* d_in, const int* in_sizes, int n_in,
                              void* d_out, int out_size, void* d_ws, size_t ws_size,
                              hipStream_t stream)
{
    const float* x = (const float*)d_in[0];
    const float* W = (const float*)d_in[1];
    const float* a = (const float*)d_in[2];
    float* out = (float*)d_out;

    float* ws = (float*)d_ws;
    float* h     = ws;                           // B*N*F
    float* si    = h + BB * NN * FF;             // B*N
    float* sj    = si + BB * NN;                 // B*N
    float* keys  = sj + BB * NN;                 // B*N
    int*   sidx  = (int*)(keys + BB * NN);       // B*N
    float* ew1   = (float*)(sidx + BB * NN);     // B*N
    float* ew2   = ew1 + BB * NN;                // B*N
    float* csum1 = ew2 + BB * NN;                // B*NCH*F
    float* csum2 = csum1 + BB * NCH * FF;        // B*NCH*F
    float* ssum1 = csum2 + BB * NCH * FF;        // B*NCH
    float* ssum2 = ssum1 + BB * NCH;             // B*NCH
    int*   cnt   = (int*)(ssum2 + BB * NCH);     // B*NCH
    int*   brows = cnt + BB * NCH;               // B*NCH*N (8.4 MB)

    hipLaunchKernelGGL(k1_h, dim3(BB * NN / K1R), dim3(256), 0, stream, x, W, a, h, si, sj, cnt);
    hipLaunchKernelGGL(k2_rank, dim3(BB * 32), dim3(1024), 0, stream, sj, keys, sidx, ew1, ew2);
    hipLaunchKernelGGL(k3a_csum, dim3(BB * NCH), dim3(128), 0, stream,
                       h, keys, sidx, si, ew1, ew2, csum1, csum2, ssum1, ssum2, cnt, brows);
    hipLaunchKernelGGL(k3se_emit, dim3(BB * NCH), dim3(256), 0, stream,
                       h, keys, sidx, si, ew1, ew2, csum1, csum2, ssum1, ssum2, cnt, brows, out);
}